// Round 5
// baseline (406.662 us; speedup 1.0000x reference)
//
#include <hip/hip_runtime.h>

#define U_    128
#define DIN   10240
#define RANK  320
#define NS    32
#define NTOT  384          // 320 (t) + 32 (B) + 32 (C)

// -------------------------------------------------------------------------
// Kernel 0: transpose x[128,10240] -> xT[10240,128]. ~3 us. (control)
// -------------------------------------------------------------------------
__global__ __launch_bounds__(256) void transpose_kernel(
    const float* __restrict__ x, float* __restrict__ xT)
{
    __shared__ float tile[32][33];
    int kb = blockIdx.x * 32, ub = blockIdx.y * 32;
    int tx = threadIdx.x, ty = threadIdx.y;      // (32, 8)
#pragma unroll
    for (int i = 0; i < 32; i += 8)
        tile[ty + i][tx] = x[(size_t)(ub + ty + i) * DIN + kb + tx];
    __syncthreads();
#pragma unroll
    for (int i = 0; i < 32; i += 8)
        xT[(size_t)(kb + ty + i) * U_ + ub + tx] = tile[tx][ty + i];
}

// -------------------------------------------------------------------------
// Kernel 1: gemmA — partial[kc][n][u] = sum_{k in chunk} xT[k,u] * W[k,n].
// (R2 version, proven.) UNCHANGED (control).
// -------------------------------------------------------------------------
template<int KCC>
__global__ __launch_bounds__(256) void gemmA_kernel(
    const float* __restrict__ xT,
    const float* __restrict__ Wd, const float* __restrict__ Wb,
    const float* __restrict__ Wc,
    float* __restrict__ partial)
{
    constexpr int KCH   = DIN / KCC;      // 160 (A-tier) / 320 (B-tier)
    constexpr int KHALF = KCH / 2;
    __shared__ float Wl[KCH][32];         // 20 KB / 40 KB

    int b  = blockIdx.x;                  // nt*KCC + kc
    int nt = b / KCC;
    int kc = b % KCC;
    int n0 = nt * 32;
    int k0 = kc * KCH;

    const float* W; int ldw, c0;
    if (nt < 10)       { W = Wd; ldw = RANK; c0 = n0; }
    else if (nt == 10) { W = Wb; ldw = NS;   c0 = 0;  }
    else               { W = Wc; ldw = NS;   c0 = 0;  }

    for (int i4 = threadIdx.x; i4 < KCH * 8; i4 += 256) {
        int r = i4 >> 3;
        int c = (i4 & 7) * 4;
        *(float4*)&Wl[r][c] =
            *(const float4*)&W[(size_t)(k0 + r) * ldw + c0 + c];
    }
    __syncthreads();

    int u    = threadIdx.x & 127;
    int half = threadIdx.x >> 7;

    float acc[32];
#pragma unroll
    for (int j = 0; j < 32; ++j) acc[j] = 0.f;

    const float* xp = xT + (size_t)(k0 + half * KHALF) * U_ + u;
    int kbase = half * KHALF;

#pragma unroll 8
    for (int k = 0; k < KHALF; ++k) {
        float xv = xp[(size_t)k * U_];                 // coalesced
        const float4* wr = (const float4*)&Wl[kbase + k][0];  // uniform bcast
#pragma unroll
        for (int j4 = 0; j4 < 8; ++j4) {
            float4 w = wr[j4];
            acc[j4 * 4 + 0] += xv * w.x;
            acc[j4 * 4 + 1] += xv * w.y;
            acc[j4 * 4 + 2] += xv * w.z;
            acc[j4 * 4 + 3] += xv * w.w;
        }
    }

    __syncthreads();
    float* comb = &Wl[0][0];
    if (half == 1) {
#pragma unroll
        for (int j = 0; j < 32; ++j) comb[j * 128 + u] = acc[j];
    }
    __syncthreads();
    if (half == 0) {
        float* out = partial + (size_t)kc * (NTOT * U_) + (size_t)n0 * U_ + u;
#pragma unroll
        for (int j = 0; j < 32; ++j)
            out[(size_t)j * U_] = acc[j] + comb[j * 128 + u];
    }
}

// -------------------------------------------------------------------------
// Kernel 2: reduce KCC k-chunk partials -> tT[320,128], B[128,32], C[128,32].
// UNCHANGED (control).
// -------------------------------------------------------------------------
template<int KCC>
__global__ __launch_bounds__(256) void reduce_kernel(
    const float* __restrict__ partial, float* __restrict__ tT,
    float* __restrict__ Bc, float* __restrict__ Cc)
{
    int e = blockIdx.x * 256 + threadIdx.x;      // 0..49151
    float s = 0.f;
#pragma unroll 8
    for (int kc = 0; kc < KCC; ++kc)
        s += partial[(size_t)kc * (NTOT * U_) + e];
    int n = e >> 7, u = e & 127;                 // e = n*128 + u
    if (n < RANK)            tT[e] = s;
    else if (n < RANK + NS)  Bc[u * NS + (n - RANK)] = s;
    else                     Cc[u * NS + (n - RANK - NS)] = s;
}

// -------------------------------------------------------------------------
// Kernel 3 (R5): delta — R2-proven shape (u-tile 8, tT staged in LDS,
// Wdt coalesced), now packing aux[u*DIN+d] = (delta, delta*x) so the
// stream kernel reads one float2 instead of recomputing/re-reading.
// Grid 80 dt x 16 ut = 1280 x 128 thr.
// -------------------------------------------------------------------------
__global__ __launch_bounds__(128) void delta_kernel(
    const float* __restrict__ tT, const float* __restrict__ Wdt,
    const float* __restrict__ b_dt, const float* __restrict__ x,
    float2* __restrict__ aux)
{
    __shared__ float ts[RANK][8];                // 10 KB
    int b   = blockIdx.x;                        // ut*80 + dt
    int dt_ = b % 80, ut = b / 80;
    int d   = dt_ * 128 + threadIdx.x;
    int u0  = ut * 8;

    for (int i4 = threadIdx.x; i4 < RANK * 2; i4 += 128) {
        int r = i4 >> 1, c = (i4 & 1) * 4;
        *(float4*)&ts[r][c] = *(const float4*)&tT[(size_t)r * U_ + u0 + c];
    }
    __syncthreads();

    float bias = b_dt[d];
    float acc[8];
#pragma unroll
    for (int i = 0; i < 8; ++i) acc[i] = bias;

#pragma unroll 4
    for (int r = 0; r < RANK; ++r) {
        float w = Wdt[(size_t)r * DIN + d];      // coalesced 512 B / block
        const float4* tp = (const float4*)&ts[r][0];   // uniform -> bcast
        float4 t0 = tp[0], t1 = tp[1];
        acc[0] += w * t0.x; acc[1] += w * t0.y;
        acc[2] += w * t0.z; acc[3] += w * t0.w;
        acc[4] += w * t1.x; acc[5] += w * t1.y;
        acc[6] += w * t1.z; acc[7] += w * t1.w;
    }
#pragma unroll
    for (int i = 0; i < 8; ++i) {
        float z  = acc[i];
        float sp = (z > 20.f) ? z : log1pf(__expf(z));
        float xv = x[(size_t)(u0 + i) * DIN + d];      // coalesced
        aux[(size_t)(u0 + i) * DIN + d] = make_float2(sp, sp * xv);
    }
}

// -------------------------------------------------------------------------
// Kernel 4 (R5): ssm_stream — m13-copy shape (the 6.29 TB/s-proven one):
// 2048 blocks x 256 thr grid-stride over float4 indices; per-instruction
// 1 KB contiguous wave access for h load / hnew store; ~30 live VGPRs so
// the compiler pipelines iterations (independent addrs); 32 waves/CU.
// Side reads: aux 10.5 MB, A 1.31 MB (L2-resident), B/C 16 KB, x 5.2 MB.
// Mandatory stream 336 MB (partial L3 absorption) => 50-65 us target.
// -------------------------------------------------------------------------
__global__ __launch_bounds__(256) void ssm_stream(
    const float2* __restrict__ aux, const float* __restrict__ x,
    const float4* __restrict__ h4, const float4* __restrict__ A4,
    const float4* __restrict__ B4, const float4* __restrict__ C4,
    const float* __restrict__ Dvec,
    float* __restrict__ y, float4* __restrict__ hn4)
{
    const int total  = U_ * DIN * 8;             // 10,485,760 float4s
    const int stride = 2048 * 256;               // 20 iters/thread
    for (int idx4 = blockIdx.x * 256 + threadIdx.x; idx4 < total;
         idx4 += stride) {
        int n4 = idx4 & 7;
        int ud = idx4 >> 3;
        int d  = ud % DIN;                       // magic-mul, ~10 VALU
        int u  = ud / DIN;

        float2 dd = aux[ud];                     // (delta, delta*x), bcast-8
        float4 hv = h4[idx4];                    // THE stream: 1 KB/wave
        float4 av = A4[(size_t)d * 8 + n4];      // L2-resident (1.31 MB)
        float4 bv = B4[u * 8 + n4];              // L1/L2 (16 KB)
        float4 cv = C4[u * 8 + n4];

        float4 hn;
        hn.x = __expf(dd.x * av.x) * hv.x + dd.y * bv.x;
        hn.y = __expf(dd.x * av.y) * hv.y + dd.y * bv.y;
        hn.z = __expf(dd.x * av.z) * hv.z + dd.y * bv.z;
        hn.w = __expf(dd.x * av.w) * hv.w + dd.y * bv.w;

        hn4[idx4] = hn;                          // 1 KB/wave store

        float p = hn.x * cv.x + hn.y * cv.y + hn.z * cv.z + hn.w * cv.w;
        p += __shfl_xor(p, 4, 8);
        p += __shfl_xor(p, 2, 8);
        p += __shfl_xor(p, 1, 8);
        if (n4 == 0)
            y[ud] = p + Dvec[d] * x[ud];
    }
}

// -------------------------------------------------------------------------
extern "C" void kernel_launch(void* const* d_in, const int* in_sizes, int n_in,
                              void* d_out, int out_size, void* d_ws, size_t ws_size,
                              hipStream_t stream)
{
    const float* x   = (const float*)d_in[0];
    const float* h   = (const float*)d_in[1];
    const float* Wd  = (const float*)d_in[2];
    const float* Wdt = (const float*)d_in[3];
    const float* bdt = (const float*)d_in[4];
    const float* Wb  = (const float*)d_in[5];
    const float* Wc  = (const float*)d_in[6];
    const float* A   = (const float*)d_in[7];
    const float* Dv  = (const float*)d_in[8];

    // Tier A (KCC=64): ws = 1310720 + 64*384*128 + 49152 = 4,505,600 floats
    // (18.0 MB).  Tier B (KCC=32): 2,932,736 floats (11.7 MB, proven fit).
    const bool big = ws_size >= (size_t)4505600 * 4;
    const size_t partial_elems = (size_t)(big ? 64 : 32) * NTOT * U_;

    float* ws      = (float*)d_ws;
    float* xT      = ws;                         // 10240*128 = 1310720
    float* partial = ws + 1310720;               // KCC*384*128
    float* tT      = partial + partial_elems;    // 320*128 = 40960
    float* Bc      = tT + 40960;                 // 128*32
    float* Cc      = Bc + 4096;                  // 128*32
    // aux[U_*DIN] float2 = 2,621,440 floats, ALIASED over xT+partial
    // (xT dead after gemmA, partial dead after reduce; delta runs after
    //  reduce and reads only tT/x/Wdt). Fits both tiers:
    //   tier B: xT+partial = 1310720+1572864 = 2,883,584 >= 2,621,440.
    float2* aux = (float2*)ws;

    float* y    = (float*)d_out;                 // [128,10240]
    float* hnew = y + (size_t)U_ * DIN;          // [128,10240,32]

    dim3 tb(32, 8);
    transpose_kernel<<<dim3(DIN / 32, U_ / 32), tb, 0, stream>>>(x, xT);
    if (big) {
        gemmA_kernel<64><<<12 * 64, 256, 0, stream>>>(xT, Wd, Wb, Wc, partial);
        reduce_kernel<64><<<192, 256, 0, stream>>>(partial, tT, Bc, Cc);
    } else {
        gemmA_kernel<32><<<12 * 32, 256, 0, stream>>>(xT, Wd, Wb, Wc, partial);
        reduce_kernel<32><<<192, 256, 0, stream>>>(partial, tT, Bc, Cc);
    }
    delta_kernel<<<1280, 128, 0, stream>>>(tT, Wdt, bdt, x, aux);
    ssm_stream  <<<2048, 256, 0, stream>>>(aux, x, (const float4*)h,
                                           (const float4*)A, (const float4*)Bc,
                                           (const float4*)Cc, Dv, y,
                                           (float4*)hnew);
}